// Round 1
// baseline (191.849 us; speedup 1.0000x reference)
//
#include <hip/hip_runtime.h>
#include <math.h>

#define OUT 14
#define RATIO 2
#define NS (OUT*RATIO)      // 28 sample positions per axis
#define NPIX (OUT*OUT)      // 196
#define C_TOT 256
#define C_BLK 32            // channels per block
#define NBOX_PER_B 128
#define NTHREADS 256

__global__ __launch_bounds__(NTHREADS)
void roi_align_fpn_kernel(const float* __restrict__ f0,
                          const float* __restrict__ f1,
                          const float* __restrict__ f2,
                          const float* __restrict__ f3,
                          const float* __restrict__ boxes,
                          float* __restrict__ out)
{
    const int k   = blockIdx.x;   // roi index, 0..255
    const int cb  = blockIdx.y;   // channel block, 0..7
    const int tid = threadIdx.x;

    __shared__ int   s_ylo[NS], s_xlo[NS];
    __shared__ float s_fyh[NS], s_fyl[NS], s_fxh[NS], s_fxl[NS];

    // ---- per-roi params (uniform across block; computed redundantly) ----
    const float bx1 = boxes[k*4+0];
    const float by1 = boxes[k*4+1];
    const float bx2 = boxes[k*4+2];
    const float by2 = boxes[k*4+3];

    // LevelMapper: lvl = floor(4 + log2(sqrt(w*h)/224 + 1e-6)), clip [2,5], -2
    const float wbox = bx2 - bx1;
    const float hbox = by2 - by1;
    const float sdim = sqrtf(wbox * hbox);
    float lvlf = floorf(4.0f + log2f(sdim / 224.0f + 1e-6f));
    lvlf = fminf(fmaxf(lvlf, 2.0f), 5.0f);
    const int lidx = (int)lvlf - 2;   // 0..3

    const float* fptr;
    int H, W;
    float scale;
    if      (lidx == 0) { fptr = f0; H = 200; W = 200; scale = 0.25f;    }
    else if (lidx == 1) { fptr = f1; H = 100; W = 100; scale = 0.125f;   }
    else if (lidx == 2) { fptr = f2; H = 50;  W = 50;  scale = 0.0625f;  }
    else                { fptr = f3; H = 25;  W = 25;  scale = 0.03125f; }

    const float x1 = bx1 * scale;
    const float y1 = by1 * scale;
    const float x2 = bx2 * scale;
    const float y2 = by2 * scale;
    const float rw = fmaxf(x2 - x1, 1.0f);
    const float rh = fmaxf(y2 - y1, 1.0f);
    const float bw = rw / (float)OUT;
    const float bh = rh / (float)OUT;

    // ---- axis tables (28 per axis) ----
    if (tid < NS) {
        const int i = tid;
        const float off = ((float)i + 0.5f) / (float)RATIO;
        // y axis
        {
            const float c  = y1 + bh * off;
            const bool  v  = (c > -1.0f) && (c < (float)H);
            const float cc = fminf(fmaxf(c, 0.0f), (float)(H - 1));
            const float fl = fminf(fmaxf(floorf(cc), 0.0f), (float)(H - 2));
            const float fr = cc - fl;
            s_ylo[i] = (int)fl;
            s_fyl[i] = v ? fr         : 0.0f;
            s_fyh[i] = v ? 1.0f - fr  : 0.0f;
        }
        // x axis
        {
            const float c  = x1 + bw * off;
            const bool  v  = (c > -1.0f) && (c < (float)W);
            const float cc = fminf(fmaxf(c, 0.0f), (float)(W - 1));
            const float fl = fminf(fmaxf(floorf(cc), 0.0f), (float)(W - 2));
            const float fr = cc - fl;
            s_xlo[i] = (int)fl;
            s_fxl[i] = v ? fr         : 0.0f;
            s_fxh[i] = v ? 1.0f - fr  : 0.0f;
        }
    }
    __syncthreads();

    const int bidx = k / NBOX_PER_B;
    const size_t plane = (size_t)H * (size_t)W;
    const float* fbase = fptr + ((size_t)bidx * C_TOT + (size_t)cb * C_BLK) * plane;
    float* obase = out + ((size_t)k * C_TOT + (size_t)cb * C_BLK) * NPIX;

    const int total = C_BLK * NPIX;            // 6272
    const int iters = (total + NTHREADS - 1) / NTHREADS;  // 25

    for (int it = 0; it < iters; ++it) {
        const int e = it * NTHREADS + tid;
        if (e >= total) break;
        const int c  = e / NPIX;
        const int p  = e - c * NPIX;
        const int ph = p / OUT;
        const int pw = p - ph * OUT;

        const float* f = fbase + (size_t)c * plane;
        float acc = 0.0f;
        #pragma unroll
        for (int iy = 0; iy < RATIO; ++iy) {
            const int sy = ph * RATIO + iy;
            const int   ylo = s_ylo[sy];
            const float fyh = s_fyh[sy];
            const float fyl = s_fyl[sy];
            const float* r0 = f + (size_t)ylo * W;
            const float* r1 = r0 + W;
            #pragma unroll
            for (int ix = 0; ix < RATIO; ++ix) {
                const int sx = pw * RATIO + ix;
                const int   xlo = s_xlo[sx];
                const float fxh = s_fxh[sx];
                const float fxl = s_fxl[sx];
                acc += fyh * (fxh * r0[xlo] + fxl * r0[xlo+1])
                     + fyl * (fxh * r1[xlo] + fxl * r1[xlo+1]);
            }
        }
        obase[e] = acc * 0.25f;
    }
}

extern "C" void kernel_launch(void* const* d_in, const int* in_sizes, int n_in,
                              void* d_out, int out_size, void* d_ws, size_t ws_size,
                              hipStream_t stream) {
    const float* f0    = (const float*)d_in[0];
    const float* f1    = (const float*)d_in[1];
    const float* f2    = (const float*)d_in[2];
    const float* f3    = (const float*)d_in[3];
    const float* boxes = (const float*)d_in[4];
    float* out = (float*)d_out;

    dim3 grid(256, C_TOT / C_BLK);   // 256 rois x 8 channel-blocks
    roi_align_fpn_kernel<<<grid, NTHREADS, 0, stream>>>(f0, f1, f2, f3, boxes, out);
}

// Round 2
// 79.015 us; speedup vs baseline: 2.4280x; 2.4280x over previous
//
#include <hip/hip_runtime.h>
#include <math.h>

#define OUT 14
#define RATIO 2
#define NS (OUT*RATIO)      // 28 sample positions per axis
#define NPIX (OUT*OUT)      // 196
#define C_TOT 256
#define C_BLK 16            // channels per block
#define NWAVES 4
#define CPW (C_BLK/NWAVES)  // 4 channels per wave
#define NBOX_PER_B 128
#define NTHREADS 256
#define PATCH_CAP 1280      // floats per wave patch (area bound ~1100 + margin)

__global__ __launch_bounds__(NTHREADS)
void roi_align_fpn_kernel(const float* __restrict__ f0,
                          const float* __restrict__ f1,
                          const float* __restrict__ f2,
                          const float* __restrict__ f3,
                          const float* __restrict__ boxes,
                          float* __restrict__ out)
{
    const int k    = blockIdx.x;   // roi index, 0..255
    const int cb   = blockIdx.y;   // channel block, 0..15
    const int tid  = threadIdx.x;
    const int wave = tid >> 6;
    const int lane = tid & 63;

    __shared__ float s_patch[NWAVES][PATCH_CAP];
    __shared__ int   s_ylo[NS], s_xlo[NS];
    __shared__ float s_fyh[NS], s_fyl[NS], s_fxh[NS], s_fxl[NS];

    // ---- per-roi params (uniform across block) ----
    const float bx1 = boxes[k*4+0];
    const float by1 = boxes[k*4+1];
    const float bx2 = boxes[k*4+2];
    const float by2 = boxes[k*4+3];

    // LevelMapper: lvl = floor(4 + log2(sqrt(w*h)/224 + 1e-6)), clip [2,5], -2
    const float wbox = bx2 - bx1;
    const float hbox = by2 - by1;
    const float sdim = sqrtf(wbox * hbox);
    float lvlf = floorf(4.0f + log2f(sdim / 224.0f + 1e-6f));
    lvlf = fminf(fmaxf(lvlf, 2.0f), 5.0f);
    const int lidx = (int)lvlf - 2;   // 0..3

    const float* fptr;
    int H, W;
    float scale;
    if      (lidx == 0) { fptr = f0; H = 200; W = 200; scale = 0.25f;    }
    else if (lidx == 1) { fptr = f1; H = 100; W = 100; scale = 0.125f;   }
    else if (lidx == 2) { fptr = f2; H = 50;  W = 50;  scale = 0.0625f;  }
    else                { fptr = f3; H = 25;  W = 25;  scale = 0.03125f; }

    const float x1 = bx1 * scale;
    const float y1 = by1 * scale;
    const float x2 = bx2 * scale;
    const float y2 = by2 * scale;
    const float rw = fmaxf(x2 - x1, 1.0f);
    const float rh = fmaxf(y2 - y1, 1.0f);
    const float bw = rw / (float)OUT;
    const float bh = rh / (float)OUT;

    // ---- axis tables (28 per axis) ----
    if (tid < NS) {
        const int i = tid;
        const float off = ((float)i + 0.5f) / (float)RATIO;
        {
            const float c  = y1 + bh * off;
            const bool  v  = (c > -1.0f) && (c < (float)H);
            const float cc = fminf(fmaxf(c, 0.0f), (float)(H - 1));
            const float fl = fminf(fmaxf(floorf(cc), 0.0f), (float)(H - 2));
            const float fr = cc - fl;
            s_ylo[i] = (int)fl;
            s_fyl[i] = v ? fr         : 0.0f;
            s_fyh[i] = v ? 1.0f - fr  : 0.0f;
        }
        {
            const float c  = x1 + bw * off;
            const bool  v  = (c > -1.0f) && (c < (float)W);
            const float cc = fminf(fmaxf(c, 0.0f), (float)(W - 1));
            const float fl = fminf(fmaxf(floorf(cc), 0.0f), (float)(W - 2));
            const float fr = cc - fl;
            s_xlo[i] = (int)fl;
            s_fxl[i] = v ? fr         : 0.0f;
            s_fxh[i] = v ? 1.0f - fr  : 0.0f;
        }
    }
    __syncthreads();

    // patch extent (tables are monotone nondecreasing)
    const int ymin = s_ylo[0];
    const int xmin = s_xlo[0];
    const int nrows = (s_ylo[NS-1] + 1) - ymin + 1;   // includes +1 bilinear row
    const int ncols = (s_xlo[NS-1] + 1) - xmin + 1;
    const int stridep = ncols | 1;                    // odd stride vs bank conflicts
    const int nelem = nrows * ncols;

    const int bidx = k / NBOX_PER_B;
    const size_t plane = (size_t)H * (size_t)W;
    const float* fbase = fptr + ((size_t)bidx * C_TOT + (size_t)cb * C_BLK) * plane;
    float* obase = out + ((size_t)k * C_TOT + (size_t)cb * C_BLK) * NPIX;

    float* sp = s_patch[wave];

    for (int j = 0; j < CPW; ++j) {
        const int c = wave * CPW + j;
        const float* g = fbase + (size_t)c * plane + (size_t)ymin * W + xmin;

        // ---- stage patch: coalesced wave loads ----
        for (int i = lane; i < nelem; i += 64) {
            const int r  = i / ncols;          // runtime div, hidden under load latency
            const int cc = i - r * ncols;
            const int di = r * stridep + cc;
            if (di < PATCH_CAP) sp[di] = g[(size_t)r * W + cc];
        }
        __syncthreads();

        // ---- bilinear from LDS ----
        for (int p = lane; p < NPIX; p += 64) {
            const int ph = p / OUT;
            const int pw = p - ph * OUT;
            float acc = 0.0f;
            #pragma unroll
            for (int iy = 0; iy < RATIO; ++iy) {
                const int sy = ph * RATIO + iy;
                const int ry = s_ylo[sy] - ymin;
                const float fyh = s_fyh[sy];
                const float fyl = s_fyl[sy];
                const float* r0 = sp + ry * stridep;
                #pragma unroll
                for (int ix = 0; ix < RATIO; ++ix) {
                    const int sx = pw * RATIO + ix;
                    const int rx = s_xlo[sx] - xmin;
                    const float fxh = s_fxh[sx];
                    const float fxl = s_fxl[sx];
                    acc += fyh * (fxh * r0[rx]         + fxl * r0[rx+1])
                         + fyl * (fxh * r0[rx+stridep] + fxl * r0[rx+stridep+1]);
                }
            }
            obase[(size_t)c * NPIX + p] = acc * 0.25f;
        }
        __syncthreads();
    }
}

extern "C" void kernel_launch(void* const* d_in, const int* in_sizes, int n_in,
                              void* d_out, int out_size, void* d_ws, size_t ws_size,
                              hipStream_t stream) {
    const float* f0    = (const float*)d_in[0];
    const float* f1    = (const float*)d_in[1];
    const float* f2    = (const float*)d_in[2];
    const float* f3    = (const float*)d_in[3];
    const float* boxes = (const float*)d_in[4];
    float* out = (float*)d_out;

    dim3 grid(256, C_TOT / C_BLK);   // 256 rois x 16 channel-blocks
    roi_align_fpn_kernel<<<grid, NTHREADS, 0, stream>>>(f0, f1, f2, f3, boxes, out);
}

// Round 3
// 56.740 us; speedup vs baseline: 3.3812x; 1.3926x over previous
//
#include <hip/hip_runtime.h>
#include <math.h>

#define OUT 14
#define RATIO 2
#define NS (OUT*RATIO)      // 28 sample positions per axis
#define NPIX (OUT*OUT)      // 196
#define C_TOT 256
#define C_BLK 16            // channels per block
#define CG 4                // channels per group (float4 interleave)
#define NGROUPS (C_BLK/CG)  // 4
#define NBOX_PER_B 128
#define NTHREADS 256
#define PATCH_CAP 1280      // float4 slots (max patch ~1150 px by LevelMapper bound)

__global__ __launch_bounds__(NTHREADS)
void roi_align_fpn_kernel(const float* __restrict__ f0,
                          const float* __restrict__ f1,
                          const float* __restrict__ f2,
                          const float* __restrict__ f3,
                          const float* __restrict__ boxes,
                          float* __restrict__ out)
{
    const int k   = blockIdx.x;   // roi index, 0..255
    const int cb  = blockIdx.y;   // channel block, 0..15
    const int tid = threadIdx.x;

    __shared__ float4 s_patch[PATCH_CAP];          // 20 KB, 4 channels interleaved
    __shared__ int   s_ylo[NS], s_xlo[NS];
    __shared__ float s_fyh[NS], s_fyl[NS], s_fxh[NS], s_fxl[NS];

    // ---- per-roi params (uniform across block) ----
    const float bx1 = boxes[k*4+0];
    const float by1 = boxes[k*4+1];
    const float bx2 = boxes[k*4+2];
    const float by2 = boxes[k*4+3];

    const float wbox = bx2 - bx1;
    const float hbox = by2 - by1;
    const float sdim = sqrtf(wbox * hbox);
    float lvlf = floorf(4.0f + log2f(sdim / 224.0f + 1e-6f));
    lvlf = fminf(fmaxf(lvlf, 2.0f), 5.0f);
    const int lidx = (int)lvlf - 2;   // 0..3

    const float* fptr;
    int H, W;
    float scale;
    if      (lidx == 0) { fptr = f0; H = 200; W = 200; scale = 0.25f;    }
    else if (lidx == 1) { fptr = f1; H = 100; W = 100; scale = 0.125f;   }
    else if (lidx == 2) { fptr = f2; H = 50;  W = 50;  scale = 0.0625f;  }
    else                { fptr = f3; H = 25;  W = 25;  scale = 0.03125f; }

    const float x1 = bx1 * scale;
    const float y1 = by1 * scale;
    const float x2 = bx2 * scale;
    const float y2 = by2 * scale;
    const float rw = fmaxf(x2 - x1, 1.0f);
    const float rh = fmaxf(y2 - y1, 1.0f);
    const float bw = rw / (float)OUT;
    const float bh = rh / (float)OUT;

    // ---- axis tables (28 per axis) ----
    if (tid < NS) {
        const int i = tid;
        const float off = ((float)i + 0.5f) / (float)RATIO;
        {
            const float c  = y1 + bh * off;
            const bool  v  = (c > -1.0f) && (c < (float)H);
            const float cc = fminf(fmaxf(c, 0.0f), (float)(H - 1));
            const float fl = fminf(fmaxf(floorf(cc), 0.0f), (float)(H - 2));
            const float fr = cc - fl;
            s_ylo[i] = (int)fl;
            s_fyl[i] = v ? fr         : 0.0f;
            s_fyh[i] = v ? 1.0f - fr  : 0.0f;
        }
        {
            const float c  = x1 + bw * off;
            const bool  v  = (c > -1.0f) && (c < (float)W);
            const float cc = fminf(fmaxf(c, 0.0f), (float)(W - 1));
            const float fl = fminf(fmaxf(floorf(cc), 0.0f), (float)(W - 2));
            const float fr = cc - fl;
            s_xlo[i] = (int)fl;
            s_fxl[i] = v ? fr         : 0.0f;
            s_fxh[i] = v ? 1.0f - fr  : 0.0f;
        }
    }
    __syncthreads();

    // ---- patch extent (tables are monotone nondecreasing) ----
    const int ymin  = s_ylo[0];
    const int xmin  = s_xlo[0];
    const int nrows = s_ylo[NS-1] + 2 - ymin;   // includes +1 bilinear row
    const int ncols = s_xlo[NS-1] + 2 - xmin;
    const int stridep = ncols | 1;              // odd px stride vs bank conflicts
    const int nelem = nrows * ncols;
    const float rcpc = 1.0f / (float)ncols;

    // ---- hoist per-pixel tap state into registers (reused for all groups) ----
    const bool active = (tid < NPIX);
    int rb0 = 0, rb1 = 0, cb0 = 0, cb1 = 0;
    float wt[16];
    #pragma unroll
    for (int i = 0; i < 16; ++i) wt[i] = 0.0f;
    if (active) {
        const int ph = tid / OUT;
        const int pw = tid - ph * OUT;
        const int sy0 = 2*ph, sy1 = 2*ph + 1;
        const int sx0 = 2*pw, sx1 = 2*pw + 1;
        rb0 = (s_ylo[sy0] - ymin) * stridep;
        rb1 = (s_ylo[sy1] - ymin) * stridep;
        cb0 = s_xlo[sx0] - xmin;
        cb1 = s_xlo[sx1] - xmin;
        const float fyh_[2] = { s_fyh[sy0], s_fyh[sy1] };
        const float fyl_[2] = { s_fyl[sy0], s_fyl[sy1] };
        const float fxh_[2] = { s_fxh[sx0], s_fxh[sx1] };
        const float fxl_[2] = { s_fxl[sx0], s_fxl[sx1] };
        #pragma unroll
        for (int ys = 0; ys < 2; ++ys) {
            #pragma unroll
            for (int xs = 0; xs < 2; ++xs) {
                const int o = (ys*2 + xs) * 4;
                wt[o+0] = fyh_[ys] * fxh_[xs] * 0.25f;
                wt[o+1] = fyh_[ys] * fxl_[xs] * 0.25f;
                wt[o+2] = fyl_[ys] * fxh_[xs] * 0.25f;
                wt[o+3] = fyl_[ys] * fxl_[xs] * 0.25f;
            }
        }
    }

    const int bidx = k / NBOX_PER_B;
    const size_t plane = (size_t)H * (size_t)W;
    const float* fbase = fptr + ((size_t)bidx * C_TOT + (size_t)cb * C_BLK) * plane
                              + (size_t)ymin * W + xmin;
    float* obase = out + ((size_t)k * C_TOT + (size_t)cb * C_BLK) * NPIX;

    for (int jg = 0; jg < NGROUPS; ++jg) {
        // ---- stage 4 channels interleaved, coalesced block loads ----
        const float* g0 = fbase + (size_t)(jg*CG + 0) * plane;
        const float* g1 = fbase + (size_t)(jg*CG + 1) * plane;
        const float* g2 = fbase + (size_t)(jg*CG + 2) * plane;
        const float* g3 = fbase + (size_t)(jg*CG + 3) * plane;
        for (int i = tid; i < nelem; i += NTHREADS) {
            const int r  = (int)(((float)i + 0.5f) * rcpc);   // exact floor (margin >> err)
            const int cc = i - r * ncols;
            const int go = r * W + cc;
            const int di = r * stridep + cc;
            float4 v;
            v.x = g0[go]; v.y = g1[go]; v.z = g2[go]; v.w = g3[go];
            if (di < PATCH_CAP) s_patch[di] = v;
        }
        __syncthreads();

        // ---- bilinear: 16 x ds_read_b128, 64 FMA per pixel (4 channels) ----
        if (active) {
            float4 acc = {0.0f, 0.0f, 0.0f, 0.0f};
            #pragma unroll
            for (int ys = 0; ys < 2; ++ys) {
                const int rbase = (ys == 0) ? rb0 : rb1;
                #pragma unroll
                for (int xs = 0; xs < 2; ++xs) {
                    const int base = rbase + ((xs == 0) ? cb0 : cb1);
                    const float4 v00 = s_patch[base];
                    const float4 v01 = s_patch[base + 1];
                    const float4 v10 = s_patch[base + stridep];
                    const float4 v11 = s_patch[base + stridep + 1];
                    const int o = (ys*2 + xs) * 4;
                    const float w00 = wt[o+0], w01 = wt[o+1], w10 = wt[o+2], w11 = wt[o+3];
                    acc.x += w00*v00.x + w01*v01.x + w10*v10.x + w11*v11.x;
                    acc.y += w00*v00.y + w01*v01.y + w10*v10.y + w11*v11.y;
                    acc.z += w00*v00.z + w01*v01.z + w10*v10.z + w11*v11.z;
                    acc.w += w00*v00.w + w01*v01.w + w10*v10.w + w11*v11.w;
                }
            }
            float* ob = obase + (size_t)(jg*CG) * NPIX + tid;
            ob[0*NPIX] = acc.x;
            ob[1*NPIX] = acc.y;
            ob[2*NPIX] = acc.z;
            ob[3*NPIX] = acc.w;
        }
        __syncthreads();
    }
}

extern "C" void kernel_launch(void* const* d_in, const int* in_sizes, int n_in,
                              void* d_out, int out_size, void* d_ws, size_t ws_size,
                              hipStream_t stream) {
    const float* f0    = (const float*)d_in[0];
    const float* f1    = (const float*)d_in[1];
    const float* f2    = (const float*)d_in[2];
    const float* f3    = (const float*)d_in[3];
    const float* boxes = (const float*)d_in[4];
    float* out = (float*)d_out;

    dim3 grid(256, C_TOT / C_BLK);   // 256 rois x 16 channel-blocks
    roi_align_fpn_kernel<<<grid, NTHREADS, 0, stream>>>(f0, f1, f2, f3, boxes, out);
}

// Round 4
// 50.457 us; speedup vs baseline: 3.8022x; 1.1245x over previous
//
#include <hip/hip_runtime.h>
#include <math.h>

#define OUT 14
#define RATIO 2
#define NS (OUT*RATIO)      // 28 sample positions per axis
#define NPIX (OUT*OUT)      // 196
#define C_TOT 256
#define CG 4                // channels per block (float4 interleave)
#define NBOX_PER_B 128
#define NTHREADS 256
#define PATCH_CAP 1280      // float4 slots; worst-case unpadded patch <= ~1176

__global__ __launch_bounds__(NTHREADS)
void roi_align_fpn_kernel(const float* __restrict__ f0,
                          const float* __restrict__ f1,
                          const float* __restrict__ f2,
                          const float* __restrict__ f3,
                          const float* __restrict__ boxes,
                          float* __restrict__ out)
{
    const int k   = blockIdx.x;   // roi index, 0..255
    const int cg  = blockIdx.y;   // channel group, 0..63 (4 channels each)
    const int tid = threadIdx.x;

    __shared__ float4 s_patch[PATCH_CAP];          // 20 KB, 4 channels interleaved
    __shared__ int   s_ylo[NS], s_xlo[NS];
    __shared__ float s_fyh[NS], s_fyl[NS], s_fxh[NS], s_fxl[NS];

    // ---- per-roi params (uniform across block) ----
    const float bx1 = boxes[k*4+0];
    const float by1 = boxes[k*4+1];
    const float bx2 = boxes[k*4+2];
    const float by2 = boxes[k*4+3];

    const float wbox = bx2 - bx1;
    const float hbox = by2 - by1;
    const float sdim = sqrtf(wbox * hbox);
    float lvlf = floorf(4.0f + log2f(sdim / 224.0f + 1e-6f));
    lvlf = fminf(fmaxf(lvlf, 2.0f), 5.0f);
    const int lidx = (int)lvlf - 2;   // 0..3

    const float* fptr;
    int H, W;
    float scale;
    if      (lidx == 0) { fptr = f0; H = 200; W = 200; scale = 0.25f;    }
    else if (lidx == 1) { fptr = f1; H = 100; W = 100; scale = 0.125f;   }
    else if (lidx == 2) { fptr = f2; H = 50;  W = 50;  scale = 0.0625f;  }
    else                { fptr = f3; H = 25;  W = 25;  scale = 0.03125f; }

    const float x1 = bx1 * scale;
    const float y1 = by1 * scale;
    const float x2 = bx2 * scale;
    const float y2 = by2 * scale;
    const float rw = fmaxf(x2 - x1, 1.0f);
    const float rh = fmaxf(y2 - y1, 1.0f);
    const float bw = rw / (float)OUT;
    const float bh = rh / (float)OUT;

    // ---- axis tables (28 per axis) ----
    if (tid < NS) {
        const int i = tid;
        const float off = ((float)i + 0.5f) / (float)RATIO;
        {
            const float c  = y1 + bh * off;
            const bool  v  = (c > -1.0f) && (c < (float)H);
            const float cc = fminf(fmaxf(c, 0.0f), (float)(H - 1));
            const float fl = fminf(fmaxf(floorf(cc), 0.0f), (float)(H - 2));
            const float fr = cc - fl;
            s_ylo[i] = (int)fl;
            s_fyl[i] = v ? fr         : 0.0f;
            s_fyh[i] = v ? 1.0f - fr  : 0.0f;
        }
        {
            const float c  = x1 + bw * off;
            const bool  v  = (c > -1.0f) && (c < (float)W);
            const float cc = fminf(fmaxf(c, 0.0f), (float)(W - 1));
            const float fl = fminf(fmaxf(floorf(cc), 0.0f), (float)(W - 2));
            const float fr = cc - fl;
            s_xlo[i] = (int)fl;
            s_fxl[i] = v ? fr         : 0.0f;
            s_fxh[i] = v ? 1.0f - fr  : 0.0f;
        }
    }
    __syncthreads();

    // ---- patch extent (tables are monotone nondecreasing) ----
    const int ymin  = s_ylo[0];
    const int xmin  = s_xlo[0];
    const int nrows = s_ylo[NS-1] + 2 - ymin;   // includes +1 bilinear row
    const int ncols = s_xlo[NS-1] + 2 - xmin;
    // pad row stride to odd when it fits; worst-case tall patches fall back unpadded
    const int padded = ncols | 1;
    const int stridep = (nrows * padded <= PATCH_CAP) ? padded : ncols;
    const int nelem = nrows * ncols;
    const float rcpc = 1.0f / (float)ncols;

    // ---- hoist per-pixel tap state into registers ----
    const bool active = (tid < NPIX);
    int rb0 = 0, rb1 = 0, cbase0 = 0, cbase1 = 0;
    float wt[16];
    #pragma unroll
    for (int i = 0; i < 16; ++i) wt[i] = 0.0f;
    if (active) {
        const int ph = tid / OUT;
        const int pw = tid - ph * OUT;
        const int sy0 = 2*ph, sy1 = 2*ph + 1;
        const int sx0 = 2*pw, sx1 = 2*pw + 1;
        rb0 = (s_ylo[sy0] - ymin) * stridep;
        rb1 = (s_ylo[sy1] - ymin) * stridep;
        cbase0 = s_xlo[sx0] - xmin;
        cbase1 = s_xlo[sx1] - xmin;
        const float fyh_[2] = { s_fyh[sy0], s_fyh[sy1] };
        const float fyl_[2] = { s_fyl[sy0], s_fyl[sy1] };
        const float fxh_[2] = { s_fxh[sx0], s_fxh[sx1] };
        const float fxl_[2] = { s_fxl[sx0], s_fxl[sx1] };
        #pragma unroll
        for (int ys = 0; ys < 2; ++ys) {
            #pragma unroll
            for (int xs = 0; xs < 2; ++xs) {
                const int o = (ys*2 + xs) * 4;
                wt[o+0] = fyh_[ys] * fxh_[xs] * 0.25f;
                wt[o+1] = fyh_[ys] * fxl_[xs] * 0.25f;
                wt[o+2] = fyl_[ys] * fxh_[xs] * 0.25f;
                wt[o+3] = fyl_[ys] * fxl_[xs] * 0.25f;
            }
        }
    }

    const int bidx = k / NBOX_PER_B;
    const size_t plane = (size_t)H * (size_t)W;
    const float* fbase = fptr + ((size_t)bidx * C_TOT + (size_t)cg * CG) * plane
                              + (size_t)ymin * W + xmin;

    // ---- stage 4 channels interleaved, coalesced block loads ----
    const float* g0 = fbase;
    const float* g1 = fbase + plane;
    const float* g2 = fbase + 2*plane;
    const float* g3 = fbase + 3*plane;
    for (int i = tid; i < nelem; i += NTHREADS) {
        const int r  = (int)(((float)i + 0.5f) * rcpc);   // exact floor (margin >> err)
        const int cc = i - r * ncols;
        const int go = r * W + cc;
        const int di = r * stridep + cc;
        float4 v;
        v.x = g0[go]; v.y = g1[go]; v.z = g2[go]; v.w = g3[go];
        if (di < PATCH_CAP) s_patch[di] = v;
    }
    __syncthreads();

    // ---- bilinear: 16 x ds_read_b128, 64 FMA per pixel (4 channels) ----
    if (active) {
        float4 acc = {0.0f, 0.0f, 0.0f, 0.0f};
        #pragma unroll
        for (int ys = 0; ys < 2; ++ys) {
            const int rbase = (ys == 0) ? rb0 : rb1;
            #pragma unroll
            for (int xs = 0; xs < 2; ++xs) {
                const int base = rbase + ((xs == 0) ? cbase0 : cbase1);
                const float4 v00 = s_patch[base];
                const float4 v01 = s_patch[base + 1];
                const float4 v10 = s_patch[base + stridep];
                const float4 v11 = s_patch[base + stridep + 1];
                const int o = (ys*2 + xs) * 4;
                const float w00 = wt[o+0], w01 = wt[o+1], w10 = wt[o+2], w11 = wt[o+3];
                acc.x += w00*v00.x + w01*v01.x + w10*v10.x + w11*v11.x;
                acc.y += w00*v00.y + w01*v01.y + w10*v10.y + w11*v11.y;
                acc.z += w00*v00.z + w01*v01.z + w10*v10.z + w11*v11.z;
                acc.w += w00*v00.w + w01*v01.w + w10*v10.w + w11*v11.w;
            }
        }
        float* ob = out + ((size_t)k * C_TOT + (size_t)cg * CG) * NPIX + tid;
        ob[0*NPIX] = acc.x;
        ob[1*NPIX] = acc.y;
        ob[2*NPIX] = acc.z;
        ob[3*NPIX] = acc.w;
    }
}

extern "C" void kernel_launch(void* const* d_in, const int* in_sizes, int n_in,
                              void* d_out, int out_size, void* d_ws, size_t ws_size,
                              hipStream_t stream) {
    const float* f0    = (const float*)d_in[0];
    const float* f1    = (const float*)d_in[1];
    const float* f2    = (const float*)d_in[2];
    const float* f3    = (const float*)d_in[3];
    const float* boxes = (const float*)d_in[4];
    float* out = (float*)d_out;

    dim3 grid(256, C_TOT / CG);   // 256 rois x 64 channel-groups
    roi_align_fpn_kernel<<<grid, NTHREADS, 0, stream>>>(f0, f1, f2, f3, boxes, out);
}

// Round 5
// 43.204 us; speedup vs baseline: 4.4406x; 1.1679x over previous
//
#include <hip/hip_runtime.h>
#include <math.h>

#define OUT 14
#define RATIO 2
#define NS (OUT*RATIO)      // 28 sample positions per axis
#define NPIX (OUT*OUT)      // 196
#define C_TOT 256
#define CG 4                // channels per block (float4 interleave)
#define NBOX_PER_B 128
#define NTHREADS 256
#define PATCH_CAP 1280      // float4 slots; worst-case patch fits (see R3/R4 analysis)
#define NROI 256

// ---- workspace layout ----
#define META_INTS 8
#define META_OFF  0
#define IDX_OFF   (NROI*META_INTS*4)                 // int4 [256][196]
#define WY_OFF    (IDX_OFF + NROI*NPIX*16)           // float4 [256][196]
#define WX_OFF    (WY_OFF  + NROI*NPIX*16)           // float4 [256][196]
#define WS_NEEDED (WX_OFF  + NROI*NPIX*16)           // ~2.42 MB

// =====================================================================
// Setup kernel: one block per roi. Computes level/meta + per-pixel tap
// records (indices + separable weights, 0.25 avg factor folded into y).
// =====================================================================
__global__ __launch_bounds__(NTHREADS)
void roi_setup_kernel(const float* __restrict__ boxes,
                      int*    __restrict__ metaW,
                      int4*   __restrict__ idxW,
                      float4* __restrict__ wyW,
                      float4* __restrict__ wxW)
{
    const int k   = blockIdx.x;
    const int tid = threadIdx.x;

    __shared__ int   s_ylo[NS], s_xlo[NS];
    __shared__ float s_fyh[NS], s_fyl[NS], s_fxh[NS], s_fxl[NS];

    const float bx1 = boxes[k*4+0];
    const float by1 = boxes[k*4+1];
    const float bx2 = boxes[k*4+2];
    const float by2 = boxes[k*4+3];

    const float wbox = bx2 - bx1;
    const float hbox = by2 - by1;
    const float sdim = sqrtf(wbox * hbox);
    float lvlf = floorf(4.0f + log2f(sdim / 224.0f + 1e-6f));
    lvlf = fminf(fmaxf(lvlf, 2.0f), 5.0f);
    const int lidx = (int)lvlf - 2;   // 0..3

    int H, W;
    float scale;
    if      (lidx == 0) { H = 200; W = 200; scale = 0.25f;    }
    else if (lidx == 1) { H = 100; W = 100; scale = 0.125f;   }
    else if (lidx == 2) { H = 50;  W = 50;  scale = 0.0625f;  }
    else                { H = 25;  W = 25;  scale = 0.03125f; }

    const float x1 = bx1 * scale;
    const float y1 = by1 * scale;
    const float x2 = bx2 * scale;
    const float y2 = by2 * scale;
    const float rw = fmaxf(x2 - x1, 1.0f);
    const float rh = fmaxf(y2 - y1, 1.0f);
    const float bw = rw / (float)OUT;
    const float bh = rh / (float)OUT;

    if (tid < NS) {
        const int i = tid;
        const float off = ((float)i + 0.5f) / (float)RATIO;
        {
            const float c  = y1 + bh * off;
            const bool  v  = (c > -1.0f) && (c < (float)H);
            const float cc = fminf(fmaxf(c, 0.0f), (float)(H - 1));
            const float fl = fminf(fmaxf(floorf(cc), 0.0f), (float)(H - 2));
            const float fr = cc - fl;
            s_ylo[i] = (int)fl;
            s_fyl[i] = v ? fr         : 0.0f;
            s_fyh[i] = v ? 1.0f - fr  : 0.0f;
        }
        {
            const float c  = x1 + bw * off;
            const bool  v  = (c > -1.0f) && (c < (float)W);
            const float cc = fminf(fmaxf(c, 0.0f), (float)(W - 1));
            const float fl = fminf(fmaxf(floorf(cc), 0.0f), (float)(W - 2));
            const float fr = cc - fl;
            s_xlo[i] = (int)fl;
            s_fxl[i] = v ? fr         : 0.0f;
            s_fxh[i] = v ? 1.0f - fr  : 0.0f;
        }
    }
    __syncthreads();

    const int ymin  = s_ylo[0];
    const int xmin  = s_xlo[0];
    const int nrows = s_ylo[NS-1] + 2 - ymin;
    const int ncols = s_xlo[NS-1] + 2 - xmin;
    const int padded  = ncols | 1;
    const int stridep = (nrows * padded <= PATCH_CAP) ? padded : ncols;

    if (tid == 0) {
        int* m = metaW + k*META_INTS;
        m[0] = lidx;
        m[1] = ymin;
        m[2] = xmin;
        m[3] = nrows;
        m[4] = ncols;
        m[5] = stridep;
        m[6] = nrows * ncols;
        m[7] = __float_as_int(1.0f / (float)ncols);
    }

    if (tid < NPIX) {
        const int ph = tid / OUT;
        const int pw = tid - ph * OUT;
        const int sy0 = 2*ph, sy1 = 2*ph + 1;
        const int sx0 = 2*pw, sx1 = 2*pw + 1;
        int4 iv;
        iv.x = (s_ylo[sy0] - ymin) * stridep;   // row base 0
        iv.y = (s_ylo[sy1] - ymin) * stridep;   // row base 1
        iv.z =  s_xlo[sx0] - xmin;              // col base 0
        iv.w =  s_xlo[sx1] - xmin;              // col base 1
        idxW[k*NPIX + tid] = iv;
        float4 wy;   // 0.25 sample-average folded into y weights
        wy.x = s_fyh[sy0] * 0.25f;
        wy.y = s_fyl[sy0] * 0.25f;
        wy.z = s_fyh[sy1] * 0.25f;
        wy.w = s_fyl[sy1] * 0.25f;
        float4 wx;
        wx.x = s_fxh[sx0];
        wx.y = s_fxl[sx0];
        wx.z = s_fxh[sx1];
        wx.w = s_fxl[sx1];
        wyW[k*NPIX + tid] = wy;
        wxW[k*NPIX + tid] = wx;
    }
}

// =====================================================================
// Main kernel: grid (64 groups, 256 rois). LDS = exactly 20480 B ->
// 8 blocks/CU (wave-cap, 100% theoretical occupancy). No transcendental
// prologue: records load immediately, staging gated only by 8-dword
// uniform meta load.
// =====================================================================
__global__ __launch_bounds__(NTHREADS)
void roi_align_main_kernel(const float* __restrict__ f0,
                           const float* __restrict__ f1,
                           const float* __restrict__ f2,
                           const float* __restrict__ f3,
                           const int*    __restrict__ metaW,
                           const int4*   __restrict__ idxW,
                           const float4* __restrict__ wyW,
                           const float4* __restrict__ wxW,
                           float* __restrict__ out)
{
    const int cg  = blockIdx.x;   // channel group, 0..63
    const int k   = blockIdx.y;   // roi, 0..255
    const int tid = threadIdx.x;

    __shared__ float4 s_patch[PATCH_CAP];   // 20480 B exactly

    // ---- per-pixel records: issue first, independent of meta ----
    const bool active = (tid < NPIX);
    int4   iv = {0,0,0,0};
    float4 wy = {0,0,0,0};
    float4 wx = {0,0,0,0};
    if (active) {
        iv = idxW[k*NPIX + tid];
        wy = wyW[k*NPIX + tid];
        wx = wxW[k*NPIX + tid];
    }

    // ---- uniform meta (scalar loads) ----
    const int* m = metaW + k*META_INTS;
    const int lidx    = m[0];
    const int ymin    = m[1];
    const int xmin    = m[2];
    const int ncols   = m[4];
    const int stridep = m[5];
    const int nelem   = m[6];
    const float rcpc  = __int_as_float(m[7]);

    const float* fptr;
    int W;
    if      (lidx == 0) { fptr = f0; W = 200; }
    else if (lidx == 1) { fptr = f1; W = 100; }
    else if (lidx == 2) { fptr = f2; W = 50;  }
    else                { fptr = f3; W = 25;  }
    const size_t plane = (size_t)W * (size_t)W;

    const float* fbase = fptr
        + ((size_t)(k / NBOX_PER_B) * C_TOT + (size_t)cg * CG) * plane
        + (size_t)ymin * W + xmin;
    const float* g0 = fbase;
    const float* g1 = fbase +   plane;
    const float* g2 = fbase + 2*plane;
    const float* g3 = fbase + 3*plane;

    // ---- stage patch: 4 channels interleaved, coalesced ----
    for (int i = tid; i < nelem; i += NTHREADS) {
        const int r  = (int)(((float)i + 0.5f) * rcpc);   // exact floor (margin >> err)
        const int cc = i - r * ncols;
        const int go = r * W + cc;
        const int di = r * stridep + cc;
        float4 v;
        v.x = g0[go]; v.y = g1[go]; v.z = g2[go]; v.w = g3[go];
        if (di < PATCH_CAP) s_patch[di] = v;
    }
    __syncthreads();

    // ---- bilinear: 16 x ds_read_b128, 64 FMA + 12 weight mults ----
    if (active) {
        float4 acc = {0.0f, 0.0f, 0.0f, 0.0f};
        #pragma unroll
        for (int ys = 0; ys < 2; ++ys) {
            const int   rb = ys ? iv.y : iv.x;
            const float yh = ys ? wy.z : wy.x;
            const float yl = ys ? wy.w : wy.y;
            #pragma unroll
            for (int xs = 0; xs < 2; ++xs) {
                const int base = rb + (xs ? iv.w : iv.z);
                const float xh = xs ? wx.z : wx.x;
                const float xl = xs ? wx.w : wx.y;
                const float w00 = yh*xh, w01 = yh*xl, w10 = yl*xh, w11 = yl*xl;
                const float4 v00 = s_patch[base];
                const float4 v01 = s_patch[base + 1];
                const float4 v10 = s_patch[base + stridep];
                const float4 v11 = s_patch[base + stridep + 1];
                acc.x += w00*v00.x + w01*v01.x + w10*v10.x + w11*v11.x;
                acc.y += w00*v00.y + w01*v01.y + w10*v10.y + w11*v11.y;
                acc.z += w00*v00.z + w01*v01.z + w10*v10.z + w11*v11.z;
                acc.w += w00*v00.w + w01*v01.w + w10*v10.w + w11*v11.w;
            }
        }
        float* ob = out + ((size_t)k * C_TOT + (size_t)cg * CG) * NPIX + tid;
        ob[0*NPIX] = acc.x;
        ob[1*NPIX] = acc.y;
        ob[2*NPIX] = acc.z;
        ob[3*NPIX] = acc.w;
    }
}

// =====================================================================
// Fallback: proven R4 monolithic kernel (used only if ws too small)
// =====================================================================
__global__ __launch_bounds__(NTHREADS)
void roi_align_fpn_kernel(const float* __restrict__ f0,
                          const float* __restrict__ f1,
                          const float* __restrict__ f2,
                          const float* __restrict__ f3,
                          const float* __restrict__ boxes,
                          float* __restrict__ out)
{
    const int k   = blockIdx.x;
    const int cg  = blockIdx.y;
    const int tid = threadIdx.x;

    __shared__ float4 s_patch[PATCH_CAP];
    __shared__ int   s_ylo[NS], s_xlo[NS];
    __shared__ float s_fyh[NS], s_fyl[NS], s_fxh[NS], s_fxl[NS];

    const float bx1 = boxes[k*4+0];
    const float by1 = boxes[k*4+1];
    const float bx2 = boxes[k*4+2];
    const float by2 = boxes[k*4+3];

    const float wbox = bx2 - bx1;
    const float hbox = by2 - by1;
    const float sdim = sqrtf(wbox * hbox);
    float lvlf = floorf(4.0f + log2f(sdim / 224.0f + 1e-6f));
    lvlf = fminf(fmaxf(lvlf, 2.0f), 5.0f);
    const int lidx = (int)lvlf - 2;

    const float* fptr;
    int H, W;
    float scale;
    if      (lidx == 0) { fptr = f0; H = 200; W = 200; scale = 0.25f;    }
    else if (lidx == 1) { fptr = f1; H = 100; W = 100; scale = 0.125f;   }
    else if (lidx == 2) { fptr = f2; H = 50;  W = 50;  scale = 0.0625f;  }
    else                { fptr = f3; H = 25;  W = 25;  scale = 0.03125f; }

    const float x1 = bx1 * scale;
    const float y1 = by1 * scale;
    const float x2 = bx2 * scale;
    const float y2 = by2 * scale;
    const float rw = fmaxf(x2 - x1, 1.0f);
    const float rh = fmaxf(y2 - y1, 1.0f);
    const float bw = rw / (float)OUT;
    const float bh = rh / (float)OUT;

    if (tid < NS) {
        const int i = tid;
        const float off = ((float)i + 0.5f) / (float)RATIO;
        {
            const float c  = y1 + bh * off;
            const bool  v  = (c > -1.0f) && (c < (float)H);
            const float cc = fminf(fmaxf(c, 0.0f), (float)(H - 1));
            const float fl = fminf(fmaxf(floorf(cc), 0.0f), (float)(H - 2));
            const float fr = cc - fl;
            s_ylo[i] = (int)fl;
            s_fyl[i] = v ? fr         : 0.0f;
            s_fyh[i] = v ? 1.0f - fr  : 0.0f;
        }
        {
            const float c  = x1 + bw * off;
            const bool  v  = (c > -1.0f) && (c < (float)W);
            const float cc = fminf(fmaxf(c, 0.0f), (float)(W - 1));
            const float fl = fminf(fmaxf(floorf(cc), 0.0f), (float)(W - 2));
            const float fr = cc - fl;
            s_xlo[i] = (int)fl;
            s_fxl[i] = v ? fr         : 0.0f;
            s_fxh[i] = v ? 1.0f - fr  : 0.0f;
        }
    }
    __syncthreads();

    const int ymin  = s_ylo[0];
    const int xmin  = s_xlo[0];
    const int nrows = s_ylo[NS-1] + 2 - ymin;
    const int ncols = s_xlo[NS-1] + 2 - xmin;
    const int padded = ncols | 1;
    const int stridep = (nrows * padded <= PATCH_CAP) ? padded : ncols;
    const int nelem = nrows * ncols;
    const float rcpc = 1.0f / (float)ncols;

    const bool active = (tid < NPIX);
    int rb0 = 0, rb1 = 0, cbase0 = 0, cbase1 = 0;
    float wt[16];
    #pragma unroll
    for (int i = 0; i < 16; ++i) wt[i] = 0.0f;
    if (active) {
        const int ph = tid / OUT;
        const int pw = tid - ph * OUT;
        const int sy0 = 2*ph, sy1 = 2*ph + 1;
        const int sx0 = 2*pw, sx1 = 2*pw + 1;
        rb0 = (s_ylo[sy0] - ymin) * stridep;
        rb1 = (s_ylo[sy1] - ymin) * stridep;
        cbase0 = s_xlo[sx0] - xmin;
        cbase1 = s_xlo[sx1] - xmin;
        const float fyh_[2] = { s_fyh[sy0], s_fyh[sy1] };
        const float fyl_[2] = { s_fyl[sy0], s_fyl[sy1] };
        const float fxh_[2] = { s_fxh[sx0], s_fxh[sx1] };
        const float fxl_[2] = { s_fxl[sx0], s_fxl[sx1] };
        #pragma unroll
        for (int ys = 0; ys < 2; ++ys) {
            #pragma unroll
            for (int xs = 0; xs < 2; ++xs) {
                const int o = (ys*2 + xs) * 4;
                wt[o+0] = fyh_[ys] * fxh_[xs] * 0.25f;
                wt[o+1] = fyh_[ys] * fxl_[xs] * 0.25f;
                wt[o+2] = fyl_[ys] * fxh_[xs] * 0.25f;
                wt[o+3] = fyl_[ys] * fxl_[xs] * 0.25f;
            }
        }
    }

    const int bidx = k / NBOX_PER_B;
    const size_t plane = (size_t)H * (size_t)W;
    const float* fbase = fptr + ((size_t)bidx * C_TOT + (size_t)cg * CG) * plane
                              + (size_t)ymin * W + xmin;
    const float* g0 = fbase;
    const float* g1 = fbase + plane;
    const float* g2 = fbase + 2*plane;
    const float* g3 = fbase + 3*plane;
    for (int i = tid; i < nelem; i += NTHREADS) {
        const int r  = (int)(((float)i + 0.5f) * rcpc);
        const int cc = i - r * ncols;
        const int go = r * W + cc;
        const int di = r * stridep + cc;
        float4 v;
        v.x = g0[go]; v.y = g1[go]; v.z = g2[go]; v.w = g3[go];
        if (di < PATCH_CAP) s_patch[di] = v;
    }
    __syncthreads();

    if (active) {
        float4 acc = {0.0f, 0.0f, 0.0f, 0.0f};
        #pragma unroll
        for (int ys = 0; ys < 2; ++ys) {
            const int rbase = (ys == 0) ? rb0 : rb1;
            #pragma unroll
            for (int xs = 0; xs < 2; ++xs) {
                const int base = rbase + ((xs == 0) ? cbase0 : cbase1);
                const float4 v00 = s_patch[base];
                const float4 v01 = s_patch[base + 1];
                const float4 v10 = s_patch[base + stridep];
                const float4 v11 = s_patch[base + stridep + 1];
                const int o = (ys*2 + xs) * 4;
                const float w00 = wt[o+0], w01 = wt[o+1], w10 = wt[o+2], w11 = wt[o+3];
                acc.x += w00*v00.x + w01*v01.x + w10*v10.x + w11*v11.x;
                acc.y += w00*v00.y + w01*v01.y + w10*v10.y + w11*v11.y;
                acc.z += w00*v00.z + w01*v01.z + w10*v10.z + w11*v11.z;
                acc.w += w00*v00.w + w01*v01.w + w10*v10.w + w11*v11.w;
            }
        }
        float* ob = out + ((size_t)k * C_TOT + (size_t)cg * CG) * NPIX + tid;
        ob[0*NPIX] = acc.x;
        ob[1*NPIX] = acc.y;
        ob[2*NPIX] = acc.z;
        ob[3*NPIX] = acc.w;
    }
}

extern "C" void kernel_launch(void* const* d_in, const int* in_sizes, int n_in,
                              void* d_out, int out_size, void* d_ws, size_t ws_size,
                              hipStream_t stream) {
    const float* f0    = (const float*)d_in[0];
    const float* f1    = (const float*)d_in[1];
    const float* f2    = (const float*)d_in[2];
    const float* f3    = (const float*)d_in[3];
    const float* boxes = (const float*)d_in[4];
    float* out = (float*)d_out;

    if (ws_size >= (size_t)WS_NEEDED) {
        char* ws = (char*)d_ws;
        int*    metaW = (int*)   (ws + META_OFF);
        int4*   idxW  = (int4*)  (ws + IDX_OFF);
        float4* wyW   = (float4*)(ws + WY_OFF);
        float4* wxW   = (float4*)(ws + WX_OFF);

        roi_setup_kernel<<<NROI, NTHREADS, 0, stream>>>(boxes, metaW, idxW, wyW, wxW);
        dim3 grid(C_TOT / CG, NROI);   // x=group (same-roi blocks adjacent for L2 reuse)
        roi_align_main_kernel<<<grid, NTHREADS, 0, stream>>>(
            f0, f1, f2, f3, metaW, idxW, wyW, wxW, out);
    } else {
        dim3 grid(NROI, C_TOT / CG);
        roi_align_fpn_kernel<<<grid, NTHREADS, 0, stream>>>(f0, f1, f2, f3, boxes, out);
    }
}